// Round 1
// baseline (127.514 us; speedup 1.0000x reference)
//
#include <hip/hip_runtime.h>

// SVDLayer: per-batch Kabsch-style rotation estimate WITHOUT reflection fix.
// r_est = V U^T where H = U S V^T. Equivalent: r_est = V S^-1 V^T H^T
// (polar-decomposition transpose), computed via symmetric Jacobi on H^T H.

constexpr int NPTS    = 1024;  // points per batch
constexpr int THREADS = 256;   // 4 points / thread

__global__ __launch_bounds__(THREADS) void svd_layer_kernel(
    const float* __restrict__ cors,
    const float* __restrict__ p_src,
    float* __restrict__ out)
{
    const int b   = blockIdx.x;
    const int tid = threadIdx.x;
    const size_t base = (size_t)b * NPTS * 3;

    // 12 consecutive floats per thread = 3 x float4 = 4 points (coalesced 16B/lane)
    const float4* src4 = reinterpret_cast<const float4*>(p_src + base);
    const float4* cor4 = reinterpret_cast<const float4*>(cors  + base);
    float4 s0 = src4[tid*3+0], s1 = src4[tid*3+1], s2 = src4[tid*3+2];
    float4 c0 = cor4[tid*3+0], c1 = cor4[tid*3+1], c2 = cor4[tid*3+2];

    // unpack [x0 y0 z0 x1][y1 z1 x2 y2][z2 x3 y3 z3]
    float sx[4] = {s0.x, s0.w, s1.z, s2.y};
    float sy[4] = {s0.y, s1.x, s1.w, s2.z};
    float sz[4] = {s0.z, s1.y, s2.x, s2.w};
    float px[4] = {sx[0]+c0.x, sx[1]+c0.w, sx[2]+c1.z, sx[3]+c2.y};
    float py[4] = {sy[0]+c0.y, sy[1]+c1.x, sy[2]+c1.w, sy[3]+c2.z};
    float pz[4] = {sz[0]+c0.z, sz[1]+c1.y, sz[2]+c2.x, sz[3]+c2.w};

    // 15 partial sums: Σsrc(3), Σpred(3), Σ src_i*pred_j (9)
    float acc[15];
    #pragma unroll
    for (int i = 0; i < 15; ++i) acc[i] = 0.f;
    #pragma unroll
    for (int k = 0; k < 4; ++k) {
        acc[0]  += sx[k]; acc[1]  += sy[k]; acc[2]  += sz[k];
        acc[3]  += px[k]; acc[4]  += py[k]; acc[5]  += pz[k];
        acc[6]  += sx[k]*px[k]; acc[7]  += sx[k]*py[k]; acc[8]  += sx[k]*pz[k];
        acc[9]  += sy[k]*px[k]; acc[10] += sy[k]*py[k]; acc[11] += sy[k]*pz[k];
        acc[12] += sz[k]*px[k]; acc[13] += sz[k]*py[k]; acc[14] += sz[k]*pz[k];
    }

    // 64-lane wave reduce
    #pragma unroll
    for (int off = 32; off > 0; off >>= 1) {
        #pragma unroll
        for (int i = 0; i < 15; ++i) acc[i] += __shfl_down(acc[i], off, 64);
    }

    __shared__ float red[4][15];
    const int wave = tid >> 6, lane = tid & 63;
    if (lane == 0) {
        #pragma unroll
        for (int i = 0; i < 15; ++i) red[wave][i] = acc[i];
    }
    __syncthreads();
    if (tid != 0) return;

    // -------- thread 0: tiny 3x3 math in double --------
    double S[15];
    #pragma unroll
    for (int i = 0; i < 15; ++i)
        S[i] = (double)red[0][i] + (double)red[1][i] + (double)red[2][i] + (double)red[3][i];

    const double invN = 1.0 / (double)NPTS;
    double cs[3] = {S[0]*invN, S[1]*invN, S[2]*invN};
    double cp[3] = {S[3]*invN, S[4]*invN, S[5]*invN};

    // H[i][j] = Σ src_i pred_j − N cs_i cp_j
    double H[3][3];
    for (int i = 0; i < 3; ++i)
        for (int j = 0; j < 3; ++j)
            H[i][j] = S[6 + i*3 + j] - (double)NPTS * cs[i] * cp[j];

    // K = H^T H (symmetric PSD)
    double A[3][3];
    for (int i = 0; i < 3; ++i)
        for (int j = 0; j < 3; ++j) {
            double v = 0.0;
            for (int k = 0; k < 3; ++k) v += H[k][i] * H[k][j];
            A[i][j] = v;
        }

    // cyclic Jacobi eigendecomposition: A_orig = V diag(A_ii) V^T
    double V[3][3] = {{1,0,0},{0,1,0},{0,0,1}};
    for (int sweep = 0; sweep < 8; ++sweep) {
        for (int pi = 0; pi < 3; ++pi) {
            const int p = (pi == 2) ? 1 : 0;
            const int q = (pi == 0) ? 1 : 2;
            const double apq = A[p][q];
            if (fabs(apq) < 1e-300) continue;
            const double tau = (A[q][q] - A[p][p]) / (2.0 * apq);
            const double t   = ((tau >= 0.0) ? 1.0 : -1.0) /
                               (fabs(tau) + sqrt(1.0 + tau*tau));
            const double c   = 1.0 / sqrt(1.0 + t*t);
            const double s   = t * c;
            A[p][p] -= t * apq;
            A[q][q] += t * apq;
            A[p][q] = A[q][p] = 0.0;
            const int k = 3 - p - q;
            const double akp = A[k][p], akq = A[k][q];
            A[k][p] = A[p][k] = c*akp - s*akq;
            A[k][q] = A[q][k] = s*akp + c*akq;
            for (int r = 0; r < 3; ++r) {
                const double vrp = V[r][p], vrq = V[r][q];
                V[r][p] = c*vrp - s*vrq;
                V[r][q] = s*vrp + c*vrq;
            }
        }
    }

    // singular values of H = sqrt(eigs of K); M = V S^-1 V^T
    double inv[3];
    for (int i = 0; i < 3; ++i) {
        double w = A[i][i] > 0.0 ? A[i][i] : 0.0;
        double sv = sqrt(w);
        inv[i] = (sv > 1e-12) ? 1.0 / sv : 0.0;
    }
    double M[3][3];
    for (int i = 0; i < 3; ++i)
        for (int j = 0; j < 3; ++j) {
            double v = 0.0;
            for (int k = 0; k < 3; ++k) v += V[i][k] * inv[k] * V[j][k];
            M[i][j] = v;
        }

    // r_est = M H^T ; t = cp − R cs
    double R[3][3];
    for (int i = 0; i < 3; ++i)
        for (int j = 0; j < 3; ++j) {
            double v = 0.0;
            for (int k = 0; k < 3; ++k) v += M[i][k] * H[j][k];
            R[i][j] = v;
        }
    double tt[3];
    for (int i = 0; i < 3; ++i)
        tt[i] = cp[i] - (R[i][0]*cs[0] + R[i][1]*cs[1] + R[i][2]*cs[2]);

    float* o = out + (size_t)b * 16;
    o[0]  = (float)R[0][0]; o[1]  = (float)R[0][1]; o[2]  = (float)R[0][2]; o[3]  = (float)tt[0];
    o[4]  = (float)R[1][0]; o[5]  = (float)R[1][1]; o[6]  = (float)R[1][2]; o[7]  = (float)tt[1];
    o[8]  = (float)R[2][0]; o[9]  = (float)R[2][1]; o[10] = (float)R[2][2]; o[11] = (float)tt[2];
    o[12] = 0.f; o[13] = 0.f; o[14] = 0.f; o[15] = 1.f;
}

extern "C" void kernel_launch(void* const* d_in, const int* in_sizes, int n_in,
                              void* d_out, int out_size, void* d_ws, size_t ws_size,
                              hipStream_t stream)
{
    const float* cors  = (const float*)d_in[0];
    const float* p_src = (const float*)d_in[1];
    float* out = (float*)d_out;
    const int B = in_sizes[0] / (NPTS * 3);  // 4096
    hipLaunchKernelGGL(svd_layer_kernel, dim3(B), dim3(THREADS), 0, stream,
                       cors, p_src, out);
}